// Round 20
// baseline (218.997 us; speedup 1.0000x reference)
//
#include <hip/hip_runtime.h>
#include <hip/hip_fp16.h>

// Problem constants (from reference)
constexpr int B = 4, C = 32, H = 544, W = 960;
constexpr int HW = H * W;          // 522240
constexpr int NPIX = B * HW;       // 2088960

// CSR-gather geometry (64x32 tiles, PAD=12, 4ch/pass, 2 blocks/CU)
constexpr int TX = 64, TY = 32;            // owned OUTPUT tile
constexpr int PAD = 12;                    // |flow|<=10 provably caught; rest -> far list
constexpr int WSX = TX + 2 * PAD;          // 88
constexpr int WSY = TY + 2 * PAD;          // 56
constexpr int WPIX = WSX * WSY;            // 4928
constexpr int WS89 = 89;                   // padded window stride
constexpr int WINCELL = WSY * WS89;        // 4984 padded cells
constexpr int TILES_X = W / TX;            // 15 (exact)
constexpr int TILES_Y = H / TY;            // 17 (exact)
constexpr int NTILES = TILES_X * TILES_Y;  // 255
constexpr int TILE = TX * TY;              // 2048
constexpr int TPB = 1024;                  // 16 waves
constexpr int NW = TPB / 64;               // 16
constexpr int PPT = TILE / TPB;            // 2 pixels per thread
constexpr int WIT = (WPIX + TPB - 1) / TPB; // 5 window iters (last partial)
constexpr int CAPE = 9728;                 // entry cap (mean ~8.2K, +19%)
constexpr int MAXFAR = 64;                 // per-tile far-slot cap
constexpr int NCH = 4;                     // channels per pass
constexpr int NPASS = C / NCH;             // 8
constexpr unsigned FARCAP = 32768;

struct FarEntry { unsigned key; float a; int p; };   // key = (b*NTILES+tile)<<11 | lidx

// ---------- pass 0: rare far-flow contributions ----------
__global__ __launch_bounds__(256)
void far_scan(const float* __restrict__ flow,
              const float* __restrict__ metric,
              unsigned* __restrict__ counter,
              FarEntry* __restrict__ fl)
{
    int idx = blockIdx.x * blockDim.x + threadIdx.x;
    if (idx >= NPIX) return;
    int b = idx / HW;
    int p = idx - b * HW;
    int y = p / W;
    int x = p - y * W;

    float fx = flow[(size_t)(b * 2 + 0) * HW + p];
    float fy = flow[(size_t)(b * 2 + 1) * HW + p];
    if (fabsf(fx) <= (float)(PAD - 2) && fabsf(fy) <= (float)(PAD - 2)) return;

    float ox = (float)x + fx, oy = (float)y + fy;
    float x0f = floorf(ox), y0f = floorf(oy);
    int x0 = (int)x0f, y0 = (int)y0f;
    float wxh = ox - x0f, wxl = 1.0f - wxh;
    float wyh = oy - y0f, wyl = 1.0f - wyh;
    const int   cxs[4] = { x0, x0 + 1, x0,     x0 + 1 };
    const int   cys[4] = { y0, y0,     y0 + 1, y0 + 1 };
    const float wts[4] = { wxl * wyl, wxh * wyl, wxl * wyh, wxh * wyh };
    float m = __expf(metric[(size_t)b * HW + p]);

#pragma unroll
    for (int k = 0; k < 4; ++k) {
        int cx = cxs[k], cy = cys[k];
        if ((unsigned)cx >= (unsigned)W || (unsigned)cy >= (unsigned)H) continue;
        int tx0 = (cx >> 6) << 6;
        int ty0 = (cy >> 5) << 5;
        bool catchable = (x >= tx0 - PAD) && (x < tx0 + TX + PAD) &&
                         (y >= ty0 - PAD) && (y < ty0 + TY + PAD);
        if (!catchable) {
            unsigned slot = atomicAdd(counter, 1u);
            if (slot < FARCAP) {
                int tile = (cy >> 5) * TILES_X + (cx >> 6);
                unsigned lidx = (unsigned)(((cy - ty0) << 6) | (cx - tx0));
                fl[slot] = { ((unsigned)(b * NTILES + tile) << 11) | lidx,
                             wts[k] * m, p };
            }
        }
    }
}

// ---------- main: fused CSR build + staged gather, 4-wide ILP walk ----------
__global__ __launch_bounds__(TPB)
void splat_csr(const float* __restrict__ inp,
               const float* __restrict__ flow,
               const float* __restrict__ metric,
               const unsigned* __restrict__ counter,
               const FarEntry* __restrict__ fl,
               float* __restrict__ out)
{
    __shared__ unsigned entries[CAPE];                         // 38912 B
    __shared__ __align__(16) unsigned pool[2 * (WINCELL + MAXFAR)]; // 40384 B
    __shared__ int farPix[MAXFAR];                             //   256 B
    __shared__ unsigned wsum[NW];
    __shared__ unsigned farCnt;
    // total ~79.6 KB -> 2 blocks/CU -> 32 waves/CU

    unsigned* offs = pool;                                   // [2048] (prologue)
    uint2*    win2 = reinterpret_cast<uint2*>(pool);         // [WINCELL+MAXFAR] (apply)

    const int t    = threadIdx.x;
    const int tile = blockIdx.x;
    const int b    = blockIdx.y;
    const int tx0  = (tile % TILES_X) * TX;
    const int ty0  = (tile / TILES_X) * TY;
    const unsigned btid = (unsigned)(b * NTILES + tile);

    const float* fxp = flow + (size_t)(b * 2 + 0) * HW;
    const float* fyp = flow + (size_t)(b * 2 + 1) * HW;
    const float* mp  = metric + (size_t)b * HW;

    for (int i = t; i < TILE; i += TPB) offs[i] = 0;
    if (t == 0) farCnt = 0;
    __syncthreads();

    // ---- phase A: compute corners ONCE, count atomics, save to registers ----
    unsigned cr[WIT][4];
#pragma unroll
    for (int j = 0; j < WIT; ++j) {
#pragma unroll
        for (int k = 0; k < 4; ++k) cr[j][k] = 0xFFFF0000u;
        int i = t + j * TPB;
        if (i >= WPIX) continue;
        int wx = i % WSX, wy = i / WSX;
        int gx = tx0 - PAD + wx, gy = ty0 - PAD + wy;
        if ((unsigned)gx >= (unsigned)W || (unsigned)gy >= (unsigned)H) continue;
        int p = gy * W + gx;
        float ox = (float)gx + fxp[p];
        float oy = (float)gy + fyp[p];
        float x0f = floorf(ox), y0f = floorf(oy);
        int lx0 = (int)x0f - tx0, ly0 = (int)y0f - ty0;
        if (lx0 < -1 || lx0 >= TX || ly0 < -1 || ly0 >= TY) continue;
        float wxh = ox - x0f, wxl = 1.0f - wxh;
        float wyh = oy - y0f, wyl = 1.0f - wyh;
        float m = __expf(mp[p]);
        const float w4[4] = { wxl * wyl, wxh * wyl, wxl * wyh, wxh * wyh };
#pragma unroll
        for (int k = 0; k < 4; ++k) {
            int lx = lx0 + (k & 1), ly = ly0 + (k >> 1);
            if ((unsigned)lx < (unsigned)TX && (unsigned)ly < (unsigned)TY) {
                unsigned lidx = (unsigned)((ly << 6) + lx);
                unsigned short ha = __half_as_ushort(__float2half(w4[k] * m));
                cr[j][k] = (lidx << 16) | (unsigned)ha;
                atomicAdd(&offs[lidx], 1u);
            }
        }
    }
    unsigned farN = *counter;
    if (farN > FARCAP) farN = FARCAP;
    for (unsigned e = t; e < farN; e += TPB) {
        unsigned k = fl[e].key;
        if ((k >> 11) == btid) atomicAdd(&offs[k & 2047u], 1u);
    }
    __syncthreads();

    // ---- block exclusive prefix-sum over offs, in place (2 items/thread) ----
    {
        unsigned c0 = offs[2 * t], c1 = offs[2 * t + 1];
        unsigned s = c0 + c1;
        unsigned lane = t & 63, wv = t >> 6;
        unsigned incl = s;
#pragma unroll
        for (int d = 1; d < 64; d <<= 1) {
            unsigned u = __shfl_up(incl, d);
            if (lane >= (unsigned)d) incl += u;
        }
        if (lane == 63) wsum[wv] = incl;
        __syncthreads();
        if (t < 64) {
            unsigned v = (lane < NW) ? wsum[lane] : 0u;
            unsigned inc2 = v;
#pragma unroll
            for (int d = 1; d < 16; d <<= 1) {
                unsigned u = __shfl_up(inc2, d);
                if (lane >= (unsigned)d) inc2 += u;
            }
            if (lane < NW) wsum[lane] = inc2 - v;   // exclusive wave base
        }
        __syncthreads();
        unsigned base = wsum[wv] + (incl - s);
        offs[2 * t]     = base;
        offs[2 * t + 1] = base + c0;
    }
    __syncthreads();

    // ---- phase C: replay from registers; entry top16 = padded window offset ----
#pragma unroll
    for (int j = 0; j < WIT; ++j) {
        int i = t + j * TPB;
        unsigned enc = (unsigned)((i / WSX) * WS89 + (i % WSX));   // padded offset
#pragma unroll
        for (int k = 0; k < 4; ++k) {
            unsigned c = cr[j][k];
            unsigned lidx = c >> 16;
            if (lidx != 0xFFFFu) {
                unsigned pos = atomicAdd(&offs[lidx], 1u);
                if (pos < CAPE)
                    entries[pos] = (enc << 16) | (c & 0xFFFFu);
            }
        }
    }
    // far entries -> extra window slots (uniform apply loop, no sentinel branch)
    for (unsigned e = t; e < farN; e += TPB) {
        unsigned k = fl[e].key;
        if ((k >> 11) == btid) {
            unsigned pos = atomicAdd(&offs[k & 2047u], 1u);
            if (pos < CAPE) {
                unsigned idx = atomicAdd(&farCnt, 1u);
                if (idx < MAXFAR) {
                    farPix[idx] = fl[e].p;
                    unsigned short ha = __half_as_ushort(__float2half(fl[e].a));
                    entries[pos] = ((unsigned)(WINCELL + idx) << 16) | (unsigned)ha;
                } else {
                    entries[pos] = 0u;   // off=0, weight=0 -> harmless
                }
            }
        }
    }
    __syncthreads();

    // ---- per-slot ranges + norm reciprocal (identity assignment: row-local) ----
    int qout[PPT];
    unsigned es[PPT], ee[PPT];
    float rn[PPT];
#pragma unroll
    for (int k = 0; k < PPT; ++k) {
        int sp = t + k * TPB;
        qout[k] = (ty0 + (sp >> 6)) * W + tx0 + (sp & 63);
        unsigned end = min(offs[sp], (unsigned)CAPE);
        unsigned start = min(sp ? offs[sp - 1] : 0u, (unsigned)CAPE);
        if (start > end) start = end;
        es[k] = start; ee[k] = end;
        float n = 0.0f;
        for (unsigned e = start; e < end; ++e)
            n += __half2float(__ushort_as_half((unsigned short)(entries[e] & 0xFFFFu)));
        rn[k] = (n == 0.0f) ? 1.0f : 1.0f / n;
    }

    // ---- precompute window-pixel global offsets (invariant across passes) ----
    int wp[WIT];
#pragma unroll
    for (int j = 0; j < WIT; ++j) {
        int i = t + j * TPB;
        wp[j] = -1;
        if (i < WPIX) {
            int wx = i % WSX, wy = i / WSX;
            int gx = tx0 - PAD + wx, gy = ty0 - PAD + wy;
            if ((unsigned)gx < (unsigned)W && (unsigned)gy < (unsigned)H)
                wp[j] = gy * W + gx;
        }
    }

    // ---- initial prefetch of channels 0..3 ----
    float4 pre[WIT];
    {
        const float* s0 = inp + (size_t)(b * C) * HW;
#pragma unroll
        for (int j = 0; j < WIT; ++j)
            pre[j] = (wp[j] >= 0)
                   ? make_float4(s0[wp[j]], s0[HW + wp[j]],
                                 s0[2 * HW + wp[j]], s0[3 * HW + wp[j]])
                   : make_float4(0.f, 0.f, 0.f, 0.f);
    }
    unsigned nFar = farCnt;
    if (nFar > MAXFAR) nFar = MAXFAR;
    __syncthreads();   // offs dead; pool becomes the window

    // ---- apply: 8 passes x 4 channels, 4-wide ILP branch-free gather ----
    for (int cp = 0; cp < NPASS; ++cp) {
        const float* s0 = inp + (size_t)(b * C + NCH * cp) * HW;

        // stage prefetched quad into LDS (padded stride)
#pragma unroll
        for (int j = 0; j < WIT; ++j) {
            int i = t + j * TPB;
            if (i < WPIX) {
                __half2 h01 = __floats2half2_rn(pre[j].x, pre[j].y);
                __half2 h23 = __floats2half2_rn(pre[j].z, pre[j].w);
                win2[(i / WSX) * WS89 + (i % WSX)] =
                    make_uint2(*reinterpret_cast<unsigned*>(&h01),
                               *reinterpret_cast<unsigned*>(&h23));
            }
        }
        // stage far-source slots (rarely any)
        if (t < (int)nFar) {
            int p = farPix[t];
            __half2 h01 = __floats2half2_rn(s0[p], s0[HW + p]);
            __half2 h23 = __floats2half2_rn(s0[2 * HW + p], s0[3 * HW + p]);
            win2[WINCELL + t] = make_uint2(*reinterpret_cast<unsigned*>(&h01),
                                           *reinterpret_cast<unsigned*>(&h23));
        }
        __syncthreads();

        // issue next quad's loads early (hidden under the gather)
        if (cp + 1 < NPASS) {
            const float* n0 = inp + (size_t)(b * C + NCH * (cp + 1)) * HW;
#pragma unroll
            for (int j = 0; j < WIT; ++j)
                pre[j] = (wp[j] >= 0)
                       ? make_float4(n0[wp[j]], n0[HW + wp[j]],
                                     n0[2 * HW + wp[j]], n0[3 * HW + wp[j]])
                       : make_float4(0.f, 0.f, 0.f, 0.f);
        }

        float* o0 = out + (size_t)(b * C + NCH * cp) * HW;
#pragma unroll
        for (int k = 0; k < PPT; ++k) {
            __half2 a01 = __floats2half2_rn(0.f, 0.f);
            __half2 a23 = __floats2half2_rn(0.f, 0.f);
            __half2 b01 = __floats2half2_rn(0.f, 0.f);
            __half2 b23 = __floats2half2_rn(0.f, 0.f);
            __half2 c01 = __floats2half2_rn(0.f, 0.f);
            __half2 c23 = __floats2half2_rn(0.f, 0.f);
            __half2 d01 = __floats2half2_rn(0.f, 0.f);
            __half2 d23 = __floats2half2_rn(0.f, 0.f);
            unsigned e = es[k], eend = ee[k];
            // 4-wide: four independent entry->win chains in flight
            for (; e + 4 <= eend; e += 4) {
                unsigned ent0 = entries[e];
                unsigned ent1 = entries[e + 1];
                unsigned ent2 = entries[e + 2];
                unsigned ent3 = entries[e + 3];
                uint2 wv0 = win2[ent0 >> 16];
                uint2 wv1 = win2[ent1 >> 16];
                uint2 wv2 = win2[ent2 >> 16];
                uint2 wv3 = win2[ent3 >> 16];
                __half2 w0 = __half2half2(__ushort_as_half((unsigned short)(ent0 & 0xFFFFu)));
                __half2 w1 = __half2half2(__ushort_as_half((unsigned short)(ent1 & 0xFFFFu)));
                __half2 w2 = __half2half2(__ushort_as_half((unsigned short)(ent2 & 0xFFFFu)));
                __half2 w3 = __half2half2(__ushort_as_half((unsigned short)(ent3 & 0xFFFFu)));
                a01 = __hfma2(w0, *reinterpret_cast<__half2*>(&wv0.x), a01);
                a23 = __hfma2(w0, *reinterpret_cast<__half2*>(&wv0.y), a23);
                b01 = __hfma2(w1, *reinterpret_cast<__half2*>(&wv1.x), b01);
                b23 = __hfma2(w1, *reinterpret_cast<__half2*>(&wv1.y), b23);
                c01 = __hfma2(w2, *reinterpret_cast<__half2*>(&wv2.x), c01);
                c23 = __hfma2(w2, *reinterpret_cast<__half2*>(&wv2.y), c23);
                d01 = __hfma2(w3, *reinterpret_cast<__half2*>(&wv3.x), d01);
                d23 = __hfma2(w3, *reinterpret_cast<__half2*>(&wv3.y), d23);
            }
            for (; e < eend; ++e) {
                unsigned ent0 = entries[e];
                uint2 wv0 = win2[ent0 >> 16];
                __half2 w0 = __half2half2(__ushort_as_half((unsigned short)(ent0 & 0xFFFFu)));
                a01 = __hfma2(w0, *reinterpret_cast<__half2*>(&wv0.x), a01);
                a23 = __hfma2(w0, *reinterpret_cast<__half2*>(&wv0.y), a23);
            }
            a01 = __hadd2(__hadd2(a01, b01), __hadd2(c01, d01));
            a23 = __hadd2(__hadd2(a23, b23), __hadd2(c23, d23));
            int q = qout[k];
            o0[q]          = __low2float(a01)  * rn[k];
            o0[HW + q]     = __high2float(a01) * rn[k];
            o0[2 * HW + q] = __low2float(a23)  * rn[k];
            o0[3 * HW + q] = __high2float(a23) * rn[k];
        }
        __syncthreads();   // win consumed; safe to overwrite next pass
    }
}

// ---------- fallback path (ws too small): f32 atomics straight into d_out ----------

__global__ __launch_bounds__(256)
void splat_f32(const float* __restrict__ inp,
               const float* __restrict__ flow,
               const float* __restrict__ metric,
               float* __restrict__ out,
               float* __restrict__ norm)
{
    int idx = blockIdx.x * blockDim.x + threadIdx.x;
    if (idx >= NPIX) return;
    int b = idx / HW;
    int p = idx - b * HW;
    int y = p / W;
    int x = p - y * W;

    float fx = flow[(b * 2 + 0) * HW + p];
    float fy = flow[(b * 2 + 1) * HW + p];
    float m  = __expf(metric[b * HW + p]);

    float ox = (float)x + fx, oy = (float)y + fy;
    float x0f = floorf(ox), y0f = floorf(oy);
    int x0 = (int)x0f, y0 = (int)y0f;
    float wx1 = ox - x0f, wx0 = 1.0f - wx1;
    float wy1 = oy - y0f, wy0 = 1.0f - wy1;

    float vm[C];
    const float* inb = inp + (size_t)b * C * HW + p;
#pragma unroll
    for (int c = 0; c < C; ++c) vm[c] = inb[(size_t)c * HW] * m;

    float* outb = out + (size_t)b * C * HW;
    float* nrmb = norm + (size_t)b * HW;

    const int   cxs[4] = { x0, x0 + 1, x0,     x0 + 1 };
    const int   cys[4] = { y0, y0,     y0 + 1, y0 + 1 };
    const float wts[4] = { wx0 * wy0, wx1 * wy0, wx0 * wy1, wx1 * wy1 };

#pragma unroll
    for (int k = 0; k < 4; ++k) {
        int cx = cxs[k], cy = cys[k];
        if (cx < 0 || cx >= W || cy < 0 || cy >= H) continue;
        float wt = wts[k];
        int q = cy * W + cx;
        atomicAdd(&nrmb[q], m * wt);
#pragma unroll
        for (int c = 0; c < C; ++c)
            atomicAdd(&outb[(size_t)c * HW + q], vm[c] * wt);
    }
}

__global__ __launch_bounds__(256)
void normalize_f32(float* __restrict__ out, const float* __restrict__ norm)
{
    int t = blockIdx.x * blockDim.x + threadIdx.x;
    long long base = (long long)t * 4;
    if (base >= (long long)B * C * HW) return;
    long long b = base / ((long long)C * HW);
    long long q = base % HW;

    float4 o = *reinterpret_cast<float4*>(out + base);
    float4 n = *reinterpret_cast<const float4*>(norm + b * HW + q);
    o.x /= (n.x == 0.0f ? 1.0f : n.x);
    o.y /= (n.y == 0.0f ? 1.0f : n.y);
    o.z /= (n.z == 0.0f ? 1.0f : n.z);
    o.w /= (n.w == 0.0f ? 1.0f : n.w);
    *reinterpret_cast<float4*>(out + base) = o;
}

extern "C" void kernel_launch(void* const* d_in, const int* in_sizes, int n_in,
                              void* d_out, int out_size, void* d_ws, size_t ws_size,
                              hipStream_t stream) {
    const float* tenInput  = (const float*)d_in[0];
    const float* tenFlow   = (const float*)d_in[1];
    const float* tenMetric = (const float*)d_in[2];
    float* out = (float*)d_out;

    const size_t need = 16 + (size_t)FARCAP * sizeof(FarEntry);   // ~384 KB

    if (ws_size >= need) {
        unsigned* counter = (unsigned*)d_ws;
        FarEntry* fl = (FarEntry*)((char*)d_ws + 16);

        hipMemsetAsync(counter, 0, 16, stream);
        far_scan<<<(NPIX + 255) / 256, 256, 0, stream>>>(tenFlow, tenMetric, counter, fl);

        dim3 grid(NTILES, B);
        splat_csr<<<grid, TPB, 0, stream>>>(tenInput, tenFlow, tenMetric,
                                            counter, fl, out);
    } else {
        float* norm = (float*)d_ws;
        hipMemsetAsync(out, 0, (size_t)B * C * HW * sizeof(float), stream);
        hipMemsetAsync(norm, 0, (size_t)NPIX * sizeof(float), stream);

        int threads = 256;
        int blocks = (NPIX + threads - 1) / threads;
        splat_f32<<<blocks, threads, 0, stream>>>(tenInput, tenFlow, tenMetric, out, norm);

        long long total = (long long)B * C * HW / 4;
        normalize_f32<<<(int)((total + threads - 1) / threads), threads, 0, stream>>>(out, norm);
    }
}

// Round 21
// 190.810 us; speedup vs baseline: 1.1477x; 1.1477x over previous
//
#include <hip/hip_runtime.h>
#include <hip/hip_fp16.h>

// Problem constants (from reference)
constexpr int B = 4, C = 32, H = 544, W = 960;
constexpr int HW = H * W;          // 522240
constexpr int NPIX = B * HW;       // 2088960

// CSR-gather geometry (64x32 tiles, PAD=12, 4ch/pass, 2 blocks/CU)
constexpr int TX = 64, TY = 32;            // owned OUTPUT tile
constexpr int PAD = 12;                    // |flow|<=10 provably caught; rest -> far list
constexpr int WSX = TX + 2 * PAD;          // 88
constexpr int WSY = TY + 2 * PAD;          // 56
constexpr int WPIX = WSX * WSY;            // 4928
constexpr int WS89 = 89;                   // padded window stride
constexpr int WINCELL = WSY * WS89;        // 4984 padded cells
constexpr int TILES_X = W / TX;            // 15 (exact)
constexpr int TILES_Y = H / TY;            // 17 (exact)
constexpr int NTILES = TILES_X * TILES_Y;  // 255
constexpr int TILE = TX * TY;              // 2048
constexpr int TPB = 1024;                  // 16 waves
constexpr int NW = TPB / 64;               // 16
constexpr int PPT = TILE / TPB;            // 2 pixels per thread
constexpr int WIT = (WPIX + TPB - 1) / TPB; // 5 window iters (last partial)
constexpr int CAPE = 9728;                 // entry cap (mean ~8.2K, +19%)
constexpr int MAXFAR = 64;                 // per-tile far-slot cap
constexpr int NCH = 4;                     // channels per pass
constexpr int NPASS = C / NCH;             // 8
constexpr unsigned FARCAP = 32768;

struct FarEntry { unsigned key; float a; int p; };   // key = (b*NTILES+tile)<<11 | lidx

// ---------- pass 0: rare far-flow contributions ----------
__global__ __launch_bounds__(256)
void far_scan(const float* __restrict__ flow,
              const float* __restrict__ metric,
              unsigned* __restrict__ counter,
              FarEntry* __restrict__ fl)
{
    int idx = blockIdx.x * blockDim.x + threadIdx.x;
    if (idx >= NPIX) return;
    int b = idx / HW;
    int p = idx - b * HW;
    int y = p / W;
    int x = p - y * W;

    float fx = flow[(size_t)(b * 2 + 0) * HW + p];
    float fy = flow[(size_t)(b * 2 + 1) * HW + p];
    if (fabsf(fx) <= (float)(PAD - 2) && fabsf(fy) <= (float)(PAD - 2)) return;

    float ox = (float)x + fx, oy = (float)y + fy;
    float x0f = floorf(ox), y0f = floorf(oy);
    int x0 = (int)x0f, y0 = (int)y0f;
    float wxh = ox - x0f, wxl = 1.0f - wxh;
    float wyh = oy - y0f, wyl = 1.0f - wyh;
    const int   cxs[4] = { x0, x0 + 1, x0,     x0 + 1 };
    const int   cys[4] = { y0, y0,     y0 + 1, y0 + 1 };
    const float wts[4] = { wxl * wyl, wxh * wyl, wxl * wyh, wxh * wyh };
    float m = __expf(metric[(size_t)b * HW + p]);

#pragma unroll
    for (int k = 0; k < 4; ++k) {
        int cx = cxs[k], cy = cys[k];
        if ((unsigned)cx >= (unsigned)W || (unsigned)cy >= (unsigned)H) continue;
        int tx0 = (cx >> 6) << 6;
        int ty0 = (cy >> 5) << 5;
        bool catchable = (x >= tx0 - PAD) && (x < tx0 + TX + PAD) &&
                         (y >= ty0 - PAD) && (y < ty0 + TY + PAD);
        if (!catchable) {
            unsigned slot = atomicAdd(counter, 1u);
            if (slot < FARCAP) {
                int tile = (cy >> 5) * TILES_X + (cx >> 6);
                unsigned lidx = (unsigned)(((cy - ty0) << 6) | (cx - tx0));
                fl[slot] = { ((unsigned)(b * NTILES + tile) << 11) | lidx,
                             wts[k] * m, p };
            }
        }
    }
}

// ---------- main: fused CSR build + staged gather (padded window stride) ----------
__global__ __launch_bounds__(TPB)
void splat_csr(const float* __restrict__ inp,
               const float* __restrict__ flow,
               const float* __restrict__ metric,
               const unsigned* __restrict__ counter,
               const FarEntry* __restrict__ fl,
               float* __restrict__ out)
{
    __shared__ unsigned entries[CAPE];                         // 38912 B
    __shared__ __align__(16) unsigned pool[2 * (WINCELL + MAXFAR)]; // 40384 B
    __shared__ int farPix[MAXFAR];                             //   256 B
    __shared__ unsigned wsum[NW];
    __shared__ unsigned farCnt;
    // total ~79.6 KB -> 2 blocks/CU -> 32 waves/CU

    unsigned* offs = pool;                                   // [2048] (prologue)
    uint2*    win2 = reinterpret_cast<uint2*>(pool);         // [WINCELL+MAXFAR] (apply)

    const int t    = threadIdx.x;
    const int tile = blockIdx.x;
    const int b    = blockIdx.y;
    const int tx0  = (tile % TILES_X) * TX;
    const int ty0  = (tile / TILES_X) * TY;
    const unsigned btid = (unsigned)(b * NTILES + tile);

    const float* fxp = flow + (size_t)(b * 2 + 0) * HW;
    const float* fyp = flow + (size_t)(b * 2 + 1) * HW;
    const float* mp  = metric + (size_t)b * HW;

    for (int i = t; i < TILE; i += TPB) offs[i] = 0;
    if (t == 0) farCnt = 0;
    __syncthreads();

    // ---- phase A: compute corners ONCE, count atomics, save to registers ----
    unsigned cr[WIT][4];
#pragma unroll
    for (int j = 0; j < WIT; ++j) {
#pragma unroll
        for (int k = 0; k < 4; ++k) cr[j][k] = 0xFFFF0000u;
        int i = t + j * TPB;
        if (i >= WPIX) continue;
        int wx = i % WSX, wy = i / WSX;
        int gx = tx0 - PAD + wx, gy = ty0 - PAD + wy;
        if ((unsigned)gx >= (unsigned)W || (unsigned)gy >= (unsigned)H) continue;
        int p = gy * W + gx;
        float ox = (float)gx + fxp[p];
        float oy = (float)gy + fyp[p];
        float x0f = floorf(ox), y0f = floorf(oy);
        int lx0 = (int)x0f - tx0, ly0 = (int)y0f - ty0;
        if (lx0 < -1 || lx0 >= TX || ly0 < -1 || ly0 >= TY) continue;
        float wxh = ox - x0f, wxl = 1.0f - wxh;
        float wyh = oy - y0f, wyl = 1.0f - wyh;
        float m = __expf(mp[p]);
        const float w4[4] = { wxl * wyl, wxh * wyl, wxl * wyh, wxh * wyh };
#pragma unroll
        for (int k = 0; k < 4; ++k) {
            int lx = lx0 + (k & 1), ly = ly0 + (k >> 1);
            if ((unsigned)lx < (unsigned)TX && (unsigned)ly < (unsigned)TY) {
                unsigned lidx = (unsigned)((ly << 6) + lx);
                unsigned short ha = __half_as_ushort(__float2half(w4[k] * m));
                cr[j][k] = (lidx << 16) | (unsigned)ha;
                atomicAdd(&offs[lidx], 1u);
            }
        }
    }
    unsigned farN = *counter;
    if (farN > FARCAP) farN = FARCAP;
    for (unsigned e = t; e < farN; e += TPB) {
        unsigned k = fl[e].key;
        if ((k >> 11) == btid) atomicAdd(&offs[k & 2047u], 1u);
    }
    __syncthreads();

    // ---- block exclusive prefix-sum over offs, in place (2 items/thread) ----
    {
        unsigned c0 = offs[2 * t], c1 = offs[2 * t + 1];
        unsigned s = c0 + c1;
        unsigned lane = t & 63, wv = t >> 6;
        unsigned incl = s;
#pragma unroll
        for (int d = 1; d < 64; d <<= 1) {
            unsigned u = __shfl_up(incl, d);
            if (lane >= (unsigned)d) incl += u;
        }
        if (lane == 63) wsum[wv] = incl;
        __syncthreads();
        if (t < 64) {
            unsigned v = (lane < NW) ? wsum[lane] : 0u;
            unsigned inc2 = v;
#pragma unroll
            for (int d = 1; d < 16; d <<= 1) {
                unsigned u = __shfl_up(inc2, d);
                if (lane >= (unsigned)d) inc2 += u;
            }
            if (lane < NW) wsum[lane] = inc2 - v;   // exclusive wave base
        }
        __syncthreads();
        unsigned base = wsum[wv] + (incl - s);
        offs[2 * t]     = base;
        offs[2 * t + 1] = base + c0;
    }
    __syncthreads();

    // ---- phase C: replay from registers; entry top16 = padded window offset ----
#pragma unroll
    for (int j = 0; j < WIT; ++j) {
        int i = t + j * TPB;
        unsigned enc = (unsigned)((i / WSX) * WS89 + (i % WSX));   // padded offset
#pragma unroll
        for (int k = 0; k < 4; ++k) {
            unsigned c = cr[j][k];
            unsigned lidx = c >> 16;
            if (lidx != 0xFFFFu) {
                unsigned pos = atomicAdd(&offs[lidx], 1u);
                if (pos < CAPE)
                    entries[pos] = (enc << 16) | (c & 0xFFFFu);
            }
        }
    }
    // far entries -> extra window slots (uniform apply loop, no sentinel branch)
    for (unsigned e = t; e < farN; e += TPB) {
        unsigned k = fl[e].key;
        if ((k >> 11) == btid) {
            unsigned pos = atomicAdd(&offs[k & 2047u], 1u);
            if (pos < CAPE) {
                unsigned idx = atomicAdd(&farCnt, 1u);
                if (idx < MAXFAR) {
                    farPix[idx] = fl[e].p;
                    unsigned short ha = __half_as_ushort(__float2half(fl[e].a));
                    entries[pos] = ((unsigned)(WINCELL + idx) << 16) | (unsigned)ha;
                } else {
                    entries[pos] = 0u;   // off=0, weight=0 -> harmless
                }
            }
        }
    }
    __syncthreads();

    // ---- per-slot ranges + norm reciprocal (identity assignment: row-local) ----
    int qout[PPT];
    unsigned es[PPT], ee[PPT];
    float rn[PPT];
#pragma unroll
    for (int k = 0; k < PPT; ++k) {
        int sp = t + k * TPB;
        qout[k] = (ty0 + (sp >> 6)) * W + tx0 + (sp & 63);
        unsigned end = min(offs[sp], (unsigned)CAPE);
        unsigned start = min(sp ? offs[sp - 1] : 0u, (unsigned)CAPE);
        if (start > end) start = end;
        es[k] = start; ee[k] = end;
        float n = 0.0f;
        for (unsigned e = start; e < end; ++e)
            n += __half2float(__ushort_as_half((unsigned short)(entries[e] & 0xFFFFu)));
        rn[k] = (n == 0.0f) ? 1.0f : 1.0f / n;
    }

    // ---- precompute window-pixel global offsets (invariant across passes) ----
    int wp[WIT];
#pragma unroll
    for (int j = 0; j < WIT; ++j) {
        int i = t + j * TPB;
        wp[j] = -1;
        if (i < WPIX) {
            int wx = i % WSX, wy = i / WSX;
            int gx = tx0 - PAD + wx, gy = ty0 - PAD + wy;
            if ((unsigned)gx < (unsigned)W && (unsigned)gy < (unsigned)H)
                wp[j] = gy * W + gx;
        }
    }

    // ---- initial prefetch of channels 0..3 ----
    float4 pre[WIT];
    {
        const float* s0 = inp + (size_t)(b * C) * HW;
#pragma unroll
        for (int j = 0; j < WIT; ++j)
            pre[j] = (wp[j] >= 0)
                   ? make_float4(s0[wp[j]], s0[HW + wp[j]],
                                 s0[2 * HW + wp[j]], s0[3 * HW + wp[j]])
                   : make_float4(0.f, 0.f, 0.f, 0.f);
    }
    unsigned nFar = farCnt;
    if (nFar > MAXFAR) nFar = MAXFAR;
    __syncthreads();   // offs dead; pool becomes the window

    // ---- apply: 8 passes x 4 channels, branch-free hfma2 gather ----
    for (int cp = 0; cp < NPASS; ++cp) {
        const float* s0 = inp + (size_t)(b * C + NCH * cp) * HW;

        // stage prefetched quad into LDS (padded stride)
#pragma unroll
        for (int j = 0; j < WIT; ++j) {
            int i = t + j * TPB;
            if (i < WPIX) {
                __half2 h01 = __floats2half2_rn(pre[j].x, pre[j].y);
                __half2 h23 = __floats2half2_rn(pre[j].z, pre[j].w);
                win2[(i / WSX) * WS89 + (i % WSX)] =
                    make_uint2(*reinterpret_cast<unsigned*>(&h01),
                               *reinterpret_cast<unsigned*>(&h23));
            }
        }
        // stage far-source slots (rarely any)
        if (t < (int)nFar) {
            int p = farPix[t];
            __half2 h01 = __floats2half2_rn(s0[p], s0[HW + p]);
            __half2 h23 = __floats2half2_rn(s0[2 * HW + p], s0[3 * HW + p]);
            win2[WINCELL + t] = make_uint2(*reinterpret_cast<unsigned*>(&h01),
                                           *reinterpret_cast<unsigned*>(&h23));
        }
        __syncthreads();

        // issue next quad's loads early (hidden under the gather)
        if (cp + 1 < NPASS) {
            const float* n0 = inp + (size_t)(b * C + NCH * (cp + 1)) * HW;
#pragma unroll
            for (int j = 0; j < WIT; ++j)
                pre[j] = (wp[j] >= 0)
                       ? make_float4(n0[wp[j]], n0[HW + wp[j]],
                                     n0[2 * HW + wp[j]], n0[3 * HW + wp[j]])
                       : make_float4(0.f, 0.f, 0.f, 0.f);
        }

        float* o0 = out + (size_t)(b * C + NCH * cp) * HW;
#pragma unroll
        for (int k = 0; k < PPT; ++k) {
            __half2 a01 = __floats2half2_rn(0.f, 0.f);
            __half2 a23 = __floats2half2_rn(0.f, 0.f);
            __half2 b01 = __floats2half2_rn(0.f, 0.f);
            __half2 b23 = __floats2half2_rn(0.f, 0.f);
            unsigned e = es[k], eend = ee[k];
            for (; e + 2 <= eend; e += 2) {
                unsigned ent0 = entries[e];
                unsigned ent1 = entries[e + 1];
                uint2 wv0 = win2[ent0 >> 16];
                uint2 wv1 = win2[ent1 >> 16];
                __half2 w0 = __half2half2(__ushort_as_half((unsigned short)(ent0 & 0xFFFFu)));
                __half2 w1 = __half2half2(__ushort_as_half((unsigned short)(ent1 & 0xFFFFu)));
                a01 = __hfma2(w0, *reinterpret_cast<__half2*>(&wv0.x), a01);
                a23 = __hfma2(w0, *reinterpret_cast<__half2*>(&wv0.y), a23);
                b01 = __hfma2(w1, *reinterpret_cast<__half2*>(&wv1.x), b01);
                b23 = __hfma2(w1, *reinterpret_cast<__half2*>(&wv1.y), b23);
            }
            if (e < eend) {
                unsigned ent0 = entries[e];
                uint2 wv0 = win2[ent0 >> 16];
                __half2 w0 = __half2half2(__ushort_as_half((unsigned short)(ent0 & 0xFFFFu)));
                a01 = __hfma2(w0, *reinterpret_cast<__half2*>(&wv0.x), a01);
                a23 = __hfma2(w0, *reinterpret_cast<__half2*>(&wv0.y), a23);
            }
            a01 = __hadd2(a01, b01);
            a23 = __hadd2(a23, b23);
            int q = qout[k];
            o0[q]          = __low2float(a01)  * rn[k];
            o0[HW + q]     = __high2float(a01) * rn[k];
            o0[2 * HW + q] = __low2float(a23)  * rn[k];
            o0[3 * HW + q] = __high2float(a23) * rn[k];
        }
        __syncthreads();   // win consumed; safe to overwrite next pass
    }
}

// ---------- fallback path (ws too small): f32 atomics straight into d_out ----------

__global__ __launch_bounds__(256)
void splat_f32(const float* __restrict__ inp,
               const float* __restrict__ flow,
               const float* __restrict__ metric,
               float* __restrict__ out,
               float* __restrict__ norm)
{
    int idx = blockIdx.x * blockDim.x + threadIdx.x;
    if (idx >= NPIX) return;
    int b = idx / HW;
    int p = idx - b * HW;
    int y = p / W;
    int x = p - y * W;

    float fx = flow[(b * 2 + 0) * HW + p];
    float fy = flow[(b * 2 + 1) * HW + p];
    float m  = __expf(metric[b * HW + p]);

    float ox = (float)x + fx, oy = (float)y + fy;
    float x0f = floorf(ox), y0f = floorf(oy);
    int x0 = (int)x0f, y0 = (int)y0f;
    float wx1 = ox - x0f, wx0 = 1.0f - wx1;
    float wy1 = oy - y0f, wy0 = 1.0f - wy1;

    float vm[C];
    const float* inb = inp + (size_t)b * C * HW + p;
#pragma unroll
    for (int c = 0; c < C; ++c) vm[c] = inb[(size_t)c * HW] * m;

    float* outb = out + (size_t)b * C * HW;
    float* nrmb = norm + (size_t)b * HW;

    const int   cxs[4] = { x0, x0 + 1, x0,     x0 + 1 };
    const int   cys[4] = { y0, y0,     y0 + 1, y0 + 1 };
    const float wts[4] = { wx0 * wy0, wx1 * wy0, wx0 * wy1, wx1 * wy1 };

#pragma unroll
    for (int k = 0; k < 4; ++k) {
        int cx = cxs[k], cy = cys[k];
        if (cx < 0 || cx >= W || cy < 0 || cy >= H) continue;
        float wt = wts[k];
        int q = cy * W + cx;
        atomicAdd(&nrmb[q], m * wt);
#pragma unroll
        for (int c = 0; c < C; ++c)
            atomicAdd(&outb[(size_t)c * HW + q], vm[c] * wt);
    }
}

__global__ __launch_bounds__(256)
void normalize_f32(float* __restrict__ out, const float* __restrict__ norm)
{
    int t = blockIdx.x * blockDim.x + threadIdx.x;
    long long base = (long long)t * 4;
    if (base >= (long long)B * C * HW) return;
    long long b = base / ((long long)C * HW);
    long long q = base % HW;

    float4 o = *reinterpret_cast<float4*>(out + base);
    float4 n = *reinterpret_cast<const float4*>(norm + b * HW + q);
    o.x /= (n.x == 0.0f ? 1.0f : n.x);
    o.y /= (n.y == 0.0f ? 1.0f : n.y);
    o.z /= (n.z == 0.0f ? 1.0f : n.z);
    o.w /= (n.w == 0.0f ? 1.0f : n.w);
    *reinterpret_cast<float4*>(out + base) = o;
}

extern "C" void kernel_launch(void* const* d_in, const int* in_sizes, int n_in,
                              void* d_out, int out_size, void* d_ws, size_t ws_size,
                              hipStream_t stream) {
    const float* tenInput  = (const float*)d_in[0];
    const float* tenFlow   = (const float*)d_in[1];
    const float* tenMetric = (const float*)d_in[2];
    float* out = (float*)d_out;

    const size_t need = 16 + (size_t)FARCAP * sizeof(FarEntry);   // ~384 KB

    if (ws_size >= need) {
        unsigned* counter = (unsigned*)d_ws;
        FarEntry* fl = (FarEntry*)((char*)d_ws + 16);

        hipMemsetAsync(counter, 0, 16, stream);
        far_scan<<<(NPIX + 255) / 256, 256, 0, stream>>>(tenFlow, tenMetric, counter, fl);

        dim3 grid(NTILES, B);
        splat_csr<<<grid, TPB, 0, stream>>>(tenInput, tenFlow, tenMetric,
                                            counter, fl, out);
    } else {
        float* norm = (float*)d_ws;
        hipMemsetAsync(out, 0, (size_t)B * C * HW * sizeof(float), stream);
        hipMemsetAsync(norm, 0, (size_t)NPIX * sizeof(float), stream);

        int threads = 256;
        int blocks = (NPIX + threads - 1) / threads;
        splat_f32<<<blocks, threads, 0, stream>>>(tenInput, tenFlow, tenMetric, out, norm);

        long long total = (long long)B * C * HW / 4;
        normalize_f32<<<(int)((total + threads - 1) / threads), threads, 0, stream>>>(out, norm);
    }
}